// Round 1
// baseline (9.706 us; speedup 1.0000x reference)
//
#include <hip/hip_runtime.h>

// QCNet_65481071402916: the quantum layer's PauliZ expectation on wire 0 of
// the Bell state (|00>+|11>)/sqrt(2) after RX(theta)⊗RZ(phi) is identically
// zero for ALL theta:
//   p(q0=0) = (c^2*|em|^2 + s^2*|ep|^2)/2,  p(q0=1) = (s^2*|em|^2 + c^2*|ep|^2)/2
// with |em|^2 == |ep|^2 (same float component magnitudes), so p0 == p1
// bitwise (float addition is commutative) and q = 0 exactly. sigmoid(0)=0.5.
// Hence the reference output is the constant [0.5, 0.5] per row, independent
// of every input — the whole CNN is dead code. Kernel = constant fill.

__global__ void qcnet_const_fill(float4* __restrict__ out4, int n4) {
    int i = blockIdx.x * blockDim.x + threadIdx.x;
    const float4 v = make_float4(0.5f, 0.5f, 0.5f, 0.5f);
    if (i < n4) out4[i] = v;
}

__global__ void qcnet_const_fill_tail(float* __restrict__ out, int start, int n) {
    int i = start + blockIdx.x * blockDim.x + threadIdx.x;
    if (i < n) out[i] = 0.5f;
}

extern "C" void kernel_launch(void* const* d_in, const int* in_sizes, int n_in,
                              void* d_out, int out_size, void* d_ws, size_t ws_size,
                              hipStream_t stream) {
    (void)d_in; (void)in_sizes; (void)n_in; (void)d_ws; (void)ws_size;
    float* out = (float*)d_out;

    int n4 = out_size / 4;            // out_size = 16384*2 = 32768 -> n4 = 8192
    if (n4 > 0) {
        int block = 256;
        int grid = (n4 + block - 1) / block;
        qcnet_const_fill<<<grid, block, 0, stream>>>((float4*)out, n4);
    }
    int rem_start = n4 * 4;
    int rem = out_size - rem_start;   // 0 for this problem, kept for safety
    if (rem > 0) {
        qcnet_const_fill_tail<<<1, 64, 0, stream>>>(out, rem_start, out_size);
    }
}